// Round 1
// baseline (1316.998 us; speedup 1.0000x reference)
//
#include <hip/hip_runtime.h>

typedef unsigned short u16;
typedef unsigned int   u32;
typedef __attribute__((ext_vector_type(8))) short bf16x8;
typedef __attribute__((ext_vector_type(4))) short bf16x4;
typedef __attribute__((ext_vector_type(4))) float f32x4;

#define LAM 0.01f

__device__ __forceinline__ u16 f2bf(float f){
  u32 u = __float_as_uint(f);
  u = u + 0x7FFFu + ((u >> 16) & 1u);
  return (u16)(u >> 16);
}

// swizzled LDS index for a [row][k] tile, pitch 128 u16; 16B chunks XOR'ed by row&15
__device__ __forceinline__ int swz(int row, int k){
  return row*128 + ((((k >> 3) ^ row) & 15) << 3) + (k & 7);
}

#define MFMA16(ac, a, b) ac = __builtin_amdgcn_mfma_f32_16x16x32_bf16((a), (b), (ac), 0, 0, 0)

#define GEMM_STEP(acc, A0,A1,A2,A3, B0,B1,B2,B3) \
  MFMA16(acc[0], A0,B0); MFMA16(acc[1], A0,B1); MFMA16(acc[2], A0,B2); MFMA16(acc[3], A0,B3); \
  MFMA16(acc[4], A1,B0); MFMA16(acc[5], A1,B1); MFMA16(acc[6], A1,B2); MFMA16(acc[7], A1,B3); \
  MFMA16(acc[8], A2,B0); MFMA16(acc[9], A2,B1); MFMA16(acc[10],A2,B2); MFMA16(acc[11],A2,B3); \
  MFMA16(acc[12],A3,B0); MFMA16(acc[13],A3,B1); MFMA16(acc[14],A3,B2); MFMA16(acc[15],A3,B3);

#define GEMM_STEP8(acc, A0,A1, B0,B1,B2,B3) \
  MFMA16(acc[0], A0,B0); MFMA16(acc[1], A0,B1); MFMA16(acc[2], A0,B2); MFMA16(acc[3], A0,B3); \
  MFMA16(acc[4], A1,B0); MFMA16(acc[5], A1,B1); MFMA16(acc[6], A1,B2); MFMA16(acc[7], A1,B3);

// ---------------- prep: cas matrix + folded transposed weights ----------------
__global__ void k_prep(const float* __restrict__ w1, const float* __restrict__ w2,
                       u16* __restrict__ Mg, u16* __restrict__ W1et, u16* __restrict__ W2et){
  int gid = blockIdx.x * 256 + threadIdx.x;
  if (gid < 16384){
    int i = gid >> 7, j = gid & 127;
    int t = (i * j) & 127;                       // exact periodic reduction
    float ang = (float)t * 0.04908738521234052f; // 2*pi/128
    Mg[gid] = f2bf(cosf(ang) + sinf(ang));
  } else if (gid < 16384 + 262144){
    int e = gid - 16384;                 // W1et[n][o][i] = w1[0,n,i,o] + w1[1,n,i,o]
    int n = e >> 15, o = (e >> 7) & 255, i = e & 127;
    float v = w1[(n*128 + i)*256 + o] + w1[((8+n)*128 + i)*256 + o];
    W1et[e] = f2bf(v);
  } else {
    int e = gid - (16384 + 262144);      // W2et[n][i][o] = w2[0,n,o,i] + w2[1,n,o,i]
    int n = e >> 15, i = (e >> 8) & 127, o = e & 255;
    float v = w2[(n*256 + o)*128 + i] + w2[((8+n)*256 + o)*128 + i];
    W2et[e] = f2bf(v);
  }
}

// ---------------- K1: A = F_H x  (per-(b,w,n) tile) ----------------
// single 32KB LDS buffer (xt reused for output staging) -> 4 blocks/CU
__launch_bounds__(256, 4)
__global__ void k_dht_fwd(const float* __restrict__ x, const u16* __restrict__ Mg,
                          u16* __restrict__ Ag){
  __shared__ u16 xt[128*128];   // [c][h] swizzled, later reused as [h'][c] staging
  int bi = blockIdx.x;
  int n = bi & 7, w = (bi >> 3) & 127, b = bi >> 10;
  int tid = threadIdx.x;
  int lane = tid & 63, wid = tid >> 6;
  int l15 = lane & 15, q = lane >> 4;
  int r0 = (wid >> 1) * 64, c0 = (wid & 1) * 64;

  // load + transpose + convert: x[b][h][w][n*128+c] -> xt[c][h]
  {
    int c = tid & 127, hg = tid >> 7;
    const float* xb = x + ((b*128)*128 + w)*1024 + n*128 + c;
    for (int it = 0; it < 32; ++it){
      int h0 = (hg + 2*it) * 2;
      float v0 = xb[h0 * 131072];
      float v1 = xb[(h0+1) * 131072];
      u32 pk = (u32)f2bf(v0) | ((u32)f2bf(v1) << 16);
      *(u32*)(&xt[swz(c, h0)]) = pk;
    }
  }
  __syncthreads();

  f32x4 acc[16];
#pragma unroll
  for (int t = 0; t < 16; ++t) acc[t] = f32x4{0.f,0.f,0.f,0.f};

#pragma unroll
  for (int ks = 0; ks < 4; ++ks){
    int kk = ks*32 + q*8;
    bf16x8 a0 = *(const bf16x8*)(Mg + (r0 +  0 + l15)*128 + kk);
    bf16x8 a1 = *(const bf16x8*)(Mg + (r0 + 16 + l15)*128 + kk);
    bf16x8 a2 = *(const bf16x8*)(Mg + (r0 + 32 + l15)*128 + kk);
    bf16x8 a3 = *(const bf16x8*)(Mg + (r0 + 48 + l15)*128 + kk);
    bf16x8 b0 = *(const bf16x8*)(&xt[swz(c0 +  0 + l15, kk)]);
    bf16x8 b1 = *(const bf16x8*)(&xt[swz(c0 + 16 + l15, kk)]);
    bf16x8 b2 = *(const bf16x8*)(&xt[swz(c0 + 32 + l15, kk)]);
    bf16x8 b3 = *(const bf16x8*)(&xt[swz(c0 + 48 + l15, kk)]);
    GEMM_STEP(acc, a0,a1,a2,a3, b0,b1,b2,b3);
  }
  __syncthreads();   // all xt fragment reads done before staging overwrites it

  // stage D[h'][c] into LDS then coalesced store
#pragma unroll
  for (int i = 0; i < 4; ++i){
    int rb = r0 + 16*i + q*4;
#pragma unroll
    for (int j = 0; j < 4; ++j){
      int col = c0 + 16*j + l15;
      f32x4 v = acc[i*4+j];
      xt[swz(rb+0, col)] = f2bf(v.x);
      xt[swz(rb+1, col)] = f2bf(v.y);
      xt[swz(rb+2, col)] = f2bf(v.z);
      xt[swz(rb+3, col)] = f2bf(v.w);
    }
  }
  __syncthreads();
  u16* Aout = Ag + ((b*128)*128 + w)*1024 + n*128;
#pragma unroll
  for (int it = 0; it < 8; ++it){
    int cid = it*256 + tid;
    int row = cid >> 4, cp = cid & 15;
    bf16x8 v = *(const bf16x8*)(&xt[row*128 + (((cp ^ row) & 15) << 3)]);
    *(bf16x8*)(Aout + row*131072 + cp*8) = v;
  }
}

// ---------------- K2 fused: F_W -> MLP -> threshold -> F_W (per-(b,h,n) tile) ----------------
// 512 threads / 8 waves, wave grid 4x2 (32x64 output each) -> 16 waves/CU
__launch_bounds__(512, 4)
__global__ void k_mlp(const u16* __restrict__ Xg, const u16* __restrict__ W1et,
                      const u16* __restrict__ W2et, const u16* __restrict__ Mg,
                      const float* __restrict__ b1g, const float* __restrict__ b2g,
                      u16* __restrict__ Ug){
  __shared__ u16 bufA[128*128];
  __shared__ u16 bufB[128*128];
  int bi = blockIdx.x;
  int n = bi & 7, h = (bi >> 3) & 127, b = bi >> 10;
  int tid = threadIdx.x;
  int lane = tid & 63, wid = tid >> 6;          // 0..7
  int l15 = lane & 15, q = lane >> 4;
  int r0 = (wid >> 1) * 32, c0 = (wid & 1) * 64;

  const u16*  Xbase  = Xg + ((b*128 + h)*128)*1024 + n*128;   // + w*1024 + c
  const u16*  W1base = W1et + n*256*128;                      // [o][c], pitch 128
  const u16*  W2base = W2et + n*128*256;                      // [c'][o], pitch 256
  const float* b1base = b1g + n*256;
  const float* b2base = b2g + n*128;

  f32x4 acc2[8], acc1[8];
#pragma unroll
  for (int t = 0; t < 8; ++t) acc2[t] = f32x4{0.f,0.f,0.f,0.f};

  for (int half = 0; half < 2; ++half){
    // ---- s1: P = X @ W1half   (A = X global rows w, k=c ; B = W1et rows o, k=c)
#pragma unroll
    for (int t = 0; t < 8; ++t) acc1[t] = f32x4{0.f,0.f,0.f,0.f};
#pragma unroll
    for (int ks = 0; ks < 4; ++ks){
      int kk = ks*32 + q*8;
      bf16x8 a0 = *(const bf16x8*)(Xbase + (r0 +  0 + l15)*1024 + kk);
      bf16x8 a1 = *(const bf16x8*)(Xbase + (r0 + 16 + l15)*1024 + kk);
      const u16* wb = W1base + (half*128 + c0 + l15)*128 + kk;
      bf16x8 b0 = *(const bf16x8*)(wb);
      bf16x8 b1 = *(const bf16x8*)(wb + 16*128);
      bf16x8 b2 = *(const bf16x8*)(wb + 32*128);
      bf16x8 b3 = *(const bf16x8*)(wb + 48*128);
      GEMM_STEP8(acc1, a0,a1, b0,b1,b2,b3);
    }
    // write P^T -> bufA  (row = o_local, k = w), packed b64
#pragma unroll
    for (int i = 0; i < 2; ++i){
      int kw = r0 + 16*i + q*4;
#pragma unroll
      for (int j = 0; j < 4; ++j){
        int row = c0 + 16*j + l15;
        f32x4 v = acc1[i*4+j];
        bf16x4 pk;
        pk.x = (short)f2bf(v.x); pk.y = (short)f2bf(v.y);
        pk.z = (short)f2bf(v.z); pk.w = (short)f2bf(v.w);
        *(bf16x4*)(&bufA[swz(row, kw)]) = pk;
      }
    }
    __syncthreads();

    // ---- s2: S1^T = P^T @ M   (A = bufA rows o, k=w ; B = M rows w', k=w)
#pragma unroll
    for (int t = 0; t < 8; ++t) acc1[t] = f32x4{0.f,0.f,0.f,0.f};
#pragma unroll
    for (int ks = 0; ks < 4; ++ks){
      int kk = ks*32 + q*8;
      bf16x8 a0 = *(const bf16x8*)(&bufA[swz(r0 +  0 + l15, kk)]);
      bf16x8 a1 = *(const bf16x8*)(&bufA[swz(r0 + 16 + l15, kk)]);
      bf16x8 b0 = *(const bf16x8*)(Mg + (c0 +  0 + l15)*128 + kk);
      bf16x8 b1 = *(const bf16x8*)(Mg + (c0 + 16 + l15)*128 + kk);
      bf16x8 b2 = *(const bf16x8*)(Mg + (c0 + 32 + l15)*128 + kk);
      bf16x8 b3 = *(const bf16x8*)(Mg + (c0 + 48 + l15)*128 + kk);
      GEMM_STEP8(acc1, a0,a1, b0,b1,b2,b3);
    }
    // relu(+b1), write o1 row-major [w][o] -> bufB, packed b64 (D rows = o, cols = w)
#pragma unroll
    for (int i = 0; i < 2; ++i){
      int ko = r0 + 16*i + q*4;
      float bs0 = b1base[half*128 + ko + 0];
      float bs1 = b1base[half*128 + ko + 1];
      float bs2 = b1base[half*128 + ko + 2];
      float bs3 = b1base[half*128 + ko + 3];
#pragma unroll
      for (int j = 0; j < 4; ++j){
        int row = c0 + 16*j + l15;
        f32x4 v = acc1[i*4+j];
        bf16x4 pk;
        pk.x = (short)f2bf(fmaxf(v.x + bs0, 0.f));
        pk.y = (short)f2bf(fmaxf(v.y + bs1, 0.f));
        pk.z = (short)f2bf(fmaxf(v.z + bs2, 0.f));
        pk.w = (short)f2bf(fmaxf(v.w + bs3, 0.f));
        *(bf16x4*)(&bufB[swz(row, ko)]) = pk;
      }
    }
    __syncthreads();

    // ---- s3: o2 += o1 @ W2half  (A = bufB rows w, k=o ; B = W2et rows c', k=o)
#pragma unroll
    for (int ks = 0; ks < 4; ++ks){
      int kk = ks*32 + q*8;
      bf16x8 a0 = *(const bf16x8*)(&bufB[swz(r0 +  0 + l15, kk)]);
      bf16x8 a1 = *(const bf16x8*)(&bufB[swz(r0 + 16 + l15, kk)]);
      const u16* wb = W2base + (c0 + l15)*256 + half*128 + kk;
      bf16x8 b0 = *(const bf16x8*)(wb);
      bf16x8 b1 = *(const bf16x8*)(wb + 16*256);
      bf16x8 b2 = *(const bf16x8*)(wb + 32*256);
      bf16x8 b3 = *(const bf16x8*)(wb + 48*256);
      GEMM_STEP8(acc2, a0,a1, b0,b1,b2,b3);
    }
    __syncthreads();
  }

  // ---- +b2, soft-threshold, write T^T -> bufA (row = c', k = w), packed b64
  {
    float b2v[4];
#pragma unroll
    for (int j = 0; j < 4; ++j) b2v[j] = b2base[c0 + 16*j + l15];
#pragma unroll
    for (int i = 0; i < 2; ++i){
      int kw = r0 + 16*i + q*4;
#pragma unroll
      for (int j = 0; j < 4; ++j){
        int row = c0 + 16*j + l15;
        f32x4 v = acc2[i*4+j];
        float t0 = v.x + b2v[j], t1 = v.y + b2v[j], t2 = v.z + b2v[j], t3 = v.w + b2v[j];
        float m0 = fmaxf(fabsf(t0) - LAM, 0.f);
        float m1 = fmaxf(fabsf(t1) - LAM, 0.f);
        float m2 = fmaxf(fabsf(t2) - LAM, 0.f);
        float m3 = fmaxf(fabsf(t3) - LAM, 0.f);
        bf16x4 pk;
        pk.x = (short)f2bf(t0 >= 0.f ? m0 : -m0);
        pk.y = (short)f2bf(t1 >= 0.f ? m1 : -m1);
        pk.z = (short)f2bf(t2 >= 0.f ? m2 : -m2);
        pk.w = (short)f2bf(t3 >= 0.f ? m3 : -m3);
        *(bf16x4*)(&bufA[swz(row, kw)]) = pk;
      }
    }
  }
  __syncthreads();

  // ---- s4: U = M @ T   (A = M rows w'', k=w ; B = bufA rows c', k=w)
#pragma unroll
  for (int t = 0; t < 8; ++t) acc1[t] = f32x4{0.f,0.f,0.f,0.f};
#pragma unroll
  for (int ks = 0; ks < 4; ++ks){
    int kk = ks*32 + q*8;
    bf16x8 a0 = *(const bf16x8*)(Mg + (r0 +  0 + l15)*128 + kk);
    bf16x8 a1 = *(const bf16x8*)(Mg + (r0 + 16 + l15)*128 + kk);
    bf16x8 b0 = *(const bf16x8*)(&bufA[swz(c0 +  0 + l15, kk)]);
    bf16x8 b1 = *(const bf16x8*)(&bufA[swz(c0 + 16 + l15, kk)]);
    bf16x8 b2 = *(const bf16x8*)(&bufA[swz(c0 + 32 + l15, kk)]);
    bf16x8 b3 = *(const bf16x8*)(&bufA[swz(c0 + 48 + l15, kk)]);
    GEMM_STEP8(acc1, a0,a1, b0,b1,b2,b3);
  }
  // stage U row-major [w''][c'] -> bufB
#pragma unroll
  for (int i = 0; i < 2; ++i){
    int rb = r0 + 16*i + q*4;
#pragma unroll
    for (int j = 0; j < 4; ++j){
      int col = c0 + 16*j + l15;
      f32x4 v = acc1[i*4+j];
      bufB[swz(rb+0, col)] = f2bf(v.x);
      bufB[swz(rb+1, col)] = f2bf(v.y);
      bufB[swz(rb+2, col)] = f2bf(v.z);
      bufB[swz(rb+3, col)] = f2bf(v.w);
    }
  }
  __syncthreads();
  u16* Ubase = Ug + ((b*128 + h)*128)*1024 + n*128;
#pragma unroll
  for (int it = 0; it < 4; ++it){
    int cid = it*512 + tid;
    int row = cid >> 4, cp = cid & 15;
    bf16x8 v = *(const bf16x8*)(&bufB[row*128 + (((cp ^ row) & 15) << 3)]);
    *(bf16x8*)(Ubase + row*1024 + cp*8) = v;
  }
}

// ---------------- K3: out = F_H U / 16384 + x ----------------
__launch_bounds__(256, 4)
__global__ void k_dht_inv(const u16* __restrict__ Ug, const u16* __restrict__ Mg,
                          const float* __restrict__ x, float* __restrict__ out){
  __shared__ u16 ut[128*128];   // [c][h] swizzled
  int bi = blockIdx.x;
  int n = bi & 7, w = (bi >> 3) & 127, b = bi >> 10;
  int tid = threadIdx.x;
  int lane = tid & 63, wid = tid >> 6;
  int l15 = lane & 15, q = lane >> 4;
  int r0 = (wid >> 1) * 64, c0 = (wid & 1) * 64;

  {
    int cp = (tid & 63) * 2, hb = (tid >> 6) * 2;
    const u16* Ub = Ug + ((b*128)*128 + w)*1024 + n*128;
#pragma unroll
    for (int it = 0; it < 16; ++it){
      int h0 = hb + it*8;
      u32 d0 = *(const u32*)(Ub + h0*131072 + cp);
      u32 d1 = *(const u32*)(Ub + (h0+1)*131072 + cp);
      u32 lo = (d0 & 0xFFFFu) | ((d1 & 0xFFFFu) << 16);
      u32 hi = (d0 >> 16) | (d1 & 0xFFFF0000u);
      *(u32*)(&ut[swz(cp,   h0)]) = lo;
      *(u32*)(&ut[swz(cp+1, h0)]) = hi;
    }
  }
  __syncthreads();

  f32x4 acc[16];
#pragma unroll
  for (int t = 0; t < 16; ++t) acc[t] = f32x4{0.f,0.f,0.f,0.f};

#pragma unroll
  for (int ks = 0; ks < 4; ++ks){
    int kk = ks*32 + q*8;
    bf16x8 a0 = *(const bf16x8*)(Mg + (r0 +  0 + l15)*128 + kk);
    bf16x8 a1 = *(const bf16x8*)(Mg + (r0 + 16 + l15)*128 + kk);
    bf16x8 a2 = *(const bf16x8*)(Mg + (r0 + 32 + l15)*128 + kk);
    bf16x8 a3 = *(const bf16x8*)(Mg + (r0 + 48 + l15)*128 + kk);
    bf16x8 b0 = *(const bf16x8*)(&ut[swz(c0 +  0 + l15, kk)]);
    bf16x8 b1 = *(const bf16x8*)(&ut[swz(c0 + 16 + l15, kk)]);
    bf16x8 b2 = *(const bf16x8*)(&ut[swz(c0 + 32 + l15, kk)]);
    bf16x8 b3 = *(const bf16x8*)(&ut[swz(c0 + 48 + l15, kk)]);
    GEMM_STEP(acc, a0,a1,a2,a3, b0,b1,b2,b3);
  }

  const float s = 1.f / 16384.f;
  int gbase = ((b*128)*128 + w)*1024 + n*128;
#pragma unroll
  for (int i = 0; i < 4; ++i){
    int hh = r0 + 16*i + q*4;
#pragma unroll
    for (int j = 0; j < 4; ++j){
      int cc = c0 + 16*j + l15;
      f32x4 v = acc[i*4+j];
      int i0 = gbase + (hh+0)*131072 + cc; out[i0] = v.x * s + x[i0];
      int i1 = gbase + (hh+1)*131072 + cc; out[i1] = v.y * s + x[i1];
      int i2 = gbase + (hh+2)*131072 + cc; out[i2] = v.z * s + x[i2];
      int i3 = gbase + (hh+3)*131072 + cc; out[i3] = v.w * s + x[i3];
    }
  }
}

extern "C" void kernel_launch(void* const* d_in, const int* in_sizes, int n_in,
                              void* d_out, int out_size, void* d_ws, size_t ws_size,
                              hipStream_t stream) {
  const float* x  = (const float*)d_in[0];
  const float* w1 = (const float*)d_in[1];
  const float* b1 = (const float*)d_in[2];
  const float* w2 = (const float*)d_in[3];
  const float* b2 = (const float*)d_in[4];
  float* out = (float*)d_out;

  // A intermediate (bf16) in first 134.2MB of d_out; folded weights in its tail.
  u16* Ag   = (u16*)d_out;
  u16* W1et = (u16*)((char*)d_out + 267386880);   // 512 KB
  u16* W2et = (u16*)((char*)d_out + 267911168);   // 512 KB
  // U intermediate (bf16) + cas matrix in workspace (~134.3 MB needed).
  u16* Ug   = (u16*)d_ws;
  u16* Mg   = (u16*)((char*)d_ws + 134217728);

  k_prep<<<2112, 256, 0, stream>>>(w1, w2, Mg, W1et, W2et);
  k_dht_fwd<<<4096, 256, 0, stream>>>(x, Mg, Ag);
  k_mlp<<<4096, 512, 0, stream>>>(Ag, W1et, W2et, Mg, b1, b2, Ug);
  k_dht_inv<<<4096, 256, 0, stream>>>(Ug, Mg, x, out);
}

// Round 2
// 1071.563 us; speedup vs baseline: 1.2290x; 1.2290x over previous
//
#include <hip/hip_runtime.h>

typedef unsigned short u16;
typedef unsigned int   u32;
typedef __attribute__((ext_vector_type(8))) short bf16x8;
typedef __attribute__((ext_vector_type(4))) short bf16x4;
typedef __attribute__((ext_vector_type(4))) float f32x4;

#define LAM 0.01f

__device__ __forceinline__ u16 f2bf(float f){
  u32 u = __float_as_uint(f);
  u = u + 0x7FFFu + ((u >> 16) & 1u);
  return (u16)(u >> 16);
}

// swizzled LDS index for a [row][k] tile, pitch 128 u16; 16B chunks XOR'ed by row&15
__device__ __forceinline__ int swz(int row, int k){
  return row*128 + ((((k >> 3) ^ row) & 15) << 3) + (k & 7);
}

#define MFMA16(ac, a, b) ac = __builtin_amdgcn_mfma_f32_16x16x32_bf16((a), (b), (ac), 0, 0, 0)

#define GEMM_STEP(acc, A0,A1,A2,A3, B0,B1,B2,B3) \
  MFMA16(acc[0], A0,B0); MFMA16(acc[1], A0,B1); MFMA16(acc[2], A0,B2); MFMA16(acc[3], A0,B3); \
  MFMA16(acc[4], A1,B0); MFMA16(acc[5], A1,B1); MFMA16(acc[6], A1,B2); MFMA16(acc[7], A1,B3); \
  MFMA16(acc[8], A2,B0); MFMA16(acc[9], A2,B1); MFMA16(acc[10],A2,B2); MFMA16(acc[11],A2,B3); \
  MFMA16(acc[12],A3,B0); MFMA16(acc[13],A3,B1); MFMA16(acc[14],A3,B2); MFMA16(acc[15],A3,B3);

// ---------------- prep: cas matrix + folded transposed weights ----------------
__global__ void k_prep(const float* __restrict__ w1, const float* __restrict__ w2,
                       u16* __restrict__ Mg, u16* __restrict__ W1et, u16* __restrict__ W2et){
  int gid = blockIdx.x * 256 + threadIdx.x;
  if (gid < 16384){
    int i = gid >> 7, j = gid & 127;
    int t = (i * j) & 127;                       // exact periodic reduction
    float ang = (float)t * 0.04908738521234052f; // 2*pi/128
    Mg[gid] = f2bf(cosf(ang) + sinf(ang));
  } else if (gid < 16384 + 262144){
    int e = gid - 16384;                 // W1et[n][o][i] = w1[0,n,i,o] + w1[1,n,i,o]
    int n = e >> 15, o = (e >> 7) & 255, i = e & 127;
    float v = w1[(n*128 + i)*256 + o] + w1[((8+n)*128 + i)*256 + o];
    W1et[e] = f2bf(v);
  } else {
    int e = gid - (16384 + 262144);      // W2et[n][i][o] = w2[0,n,o,i] + w2[1,n,o,i]
    int n = e >> 15, i = (e >> 8) & 127, o = e & 255;
    float v = w2[(n*256 + o)*128 + i] + w2[((8+n)*256 + o)*128 + i];
    W2et[e] = f2bf(v);
  }
}

// ---------------- K1: A = F_H x  (per-(b,w,n) tile) ----------------
// single 32KB LDS buffer (xt reused for output staging) -> 4 blocks/CU
__launch_bounds__(256, 4)
__global__ void k_dht_fwd(const float* __restrict__ x, const u16* __restrict__ Mg,
                          u16* __restrict__ Ag){
  __shared__ u16 xt[128*128];   // [c][h] swizzled, later reused as [h'][c] staging
  int bi = blockIdx.x;
  int n = bi & 7, w = (bi >> 3) & 127, b = bi >> 10;
  int tid = threadIdx.x;
  int lane = tid & 63, wid = tid >> 6;
  int l15 = lane & 15, q = lane >> 4;
  int r0 = (wid >> 1) * 64, c0 = (wid & 1) * 64;

  // load + transpose + convert: x[b][h][w][n*128+c] -> xt[c][h]
  {
    int c = tid & 127, hg = tid >> 7;
    const float* xb = x + ((b*128)*128 + w)*1024 + n*128 + c;
    for (int it = 0; it < 32; ++it){
      int h0 = (hg + 2*it) * 2;
      float v0 = __builtin_nontemporal_load(xb + h0 * 131072);
      float v1 = __builtin_nontemporal_load(xb + (h0+1) * 131072);
      u32 pk = (u32)f2bf(v0) | ((u32)f2bf(v1) << 16);
      *(u32*)(&xt[swz(c, h0)]) = pk;
    }
  }
  __syncthreads();

  f32x4 acc[16];
#pragma unroll
  for (int t = 0; t < 16; ++t) acc[t] = f32x4{0.f,0.f,0.f,0.f};

#pragma unroll
  for (int ks = 0; ks < 4; ++ks){
    int kk = ks*32 + q*8;
    bf16x8 a0 = *(const bf16x8*)(Mg + (r0 +  0 + l15)*128 + kk);
    bf16x8 a1 = *(const bf16x8*)(Mg + (r0 + 16 + l15)*128 + kk);
    bf16x8 a2 = *(const bf16x8*)(Mg + (r0 + 32 + l15)*128 + kk);
    bf16x8 a3 = *(const bf16x8*)(Mg + (r0 + 48 + l15)*128 + kk);
    bf16x8 b0 = *(const bf16x8*)(&xt[swz(c0 +  0 + l15, kk)]);
    bf16x8 b1 = *(const bf16x8*)(&xt[swz(c0 + 16 + l15, kk)]);
    bf16x8 b2 = *(const bf16x8*)(&xt[swz(c0 + 32 + l15, kk)]);
    bf16x8 b3 = *(const bf16x8*)(&xt[swz(c0 + 48 + l15, kk)]);
    GEMM_STEP(acc, a0,a1,a2,a3, b0,b1,b2,b3);
  }
  __syncthreads();   // all xt fragment reads done before staging overwrites it

  // stage D[h'][c] into LDS then coalesced store
#pragma unroll
  for (int i = 0; i < 4; ++i){
    int rb = r0 + 16*i + q*4;
#pragma unroll
    for (int j = 0; j < 4; ++j){
      int col = c0 + 16*j + l15;
      f32x4 v = acc[i*4+j];
      xt[swz(rb+0, col)] = f2bf(v.x);
      xt[swz(rb+1, col)] = f2bf(v.y);
      xt[swz(rb+2, col)] = f2bf(v.z);
      xt[swz(rb+3, col)] = f2bf(v.w);
    }
  }
  __syncthreads();
  u16* Aout = Ag + ((b*128)*128 + w)*1024 + n*128;
#pragma unroll
  for (int it = 0; it < 8; ++it){
    int cid = it*256 + tid;
    int row = cid >> 4, cp = cid & 15;
    bf16x8 v = *(const bf16x8*)(&xt[row*128 + (((cp ^ row) & 15) << 3)]);
    __builtin_nontemporal_store(v, (bf16x8*)(Aout + row*131072 + cp*8));
  }
}

// ---------------- K2 fused: F_W -> MLP -> threshold -> F_W (per-(b,h,n) tile) ----------------
// 4 waves, X A-fragments held in registers across both halves (X read once per wave)
__launch_bounds__(256, 2)
__global__ void k_mlp(const u16* __restrict__ Xg, const u16* __restrict__ W1et,
                      const u16* __restrict__ W2et, const u16* __restrict__ Mg,
                      const float* __restrict__ b1g, const float* __restrict__ b2g,
                      u16* __restrict__ Ug){
  __shared__ u16 bufA[128*128];
  __shared__ u16 bufB[128*128];
  int bi = blockIdx.x;
  int n = bi & 7, h = (bi >> 3) & 127, b = bi >> 10;
  int tid = threadIdx.x;
  int lane = tid & 63, wid = tid >> 6;
  int l15 = lane & 15, q = lane >> 4;
  int r0 = (wid >> 1) * 64, c0 = (wid & 1) * 64;

  const u16*  Xbase  = Xg + ((b*128 + h)*128)*1024 + n*128;   // + w*1024 + c
  const u16*  W1base = W1et + n*256*128;                      // [o][c], pitch 128
  const u16*  W2base = W2et + n*128*256;                      // [c'][o], pitch 256
  const float* b1base = b1g + n*256;
  const float* b2base = b2g + n*128;

  // X A-fragments: rows r0..r0+63, all k=128 -> 16 x bf16x8 (64 VGPR), loaded ONCE
  bf16x8 xa[16];
#pragma unroll
  for (int ks = 0; ks < 4; ++ks){
    int kk = ks*32 + q*8;
#pragma unroll
    for (int g = 0; g < 4; ++g)
      xa[ks*4+g] = *(const bf16x8*)(Xbase + (r0 + 16*g + l15)*1024 + kk);
  }

  f32x4 acc2[16], acc1[16];
#pragma unroll
  for (int t = 0; t < 16; ++t) acc2[t] = f32x4{0.f,0.f,0.f,0.f};

  for (int half = 0; half < 2; ++half){
    // ---- s1: P = X @ W1half   (A = xa regs rows w, k=c ; B = W1et rows o, k=c)
#pragma unroll
    for (int t = 0; t < 16; ++t) acc1[t] = f32x4{0.f,0.f,0.f,0.f};
#pragma unroll
    for (int ks = 0; ks < 4; ++ks){
      int kk = ks*32 + q*8;
      const u16* wb = W1base + (half*128 + c0 + l15)*128 + kk;
      bf16x8 b0 = *(const bf16x8*)(wb);
      bf16x8 b1 = *(const bf16x8*)(wb + 16*128);
      bf16x8 b2 = *(const bf16x8*)(wb + 32*128);
      bf16x8 b3 = *(const bf16x8*)(wb + 48*128);
      GEMM_STEP(acc1, xa[ks*4+0], xa[ks*4+1], xa[ks*4+2], xa[ks*4+3], b0,b1,b2,b3);
    }
    // write P^T -> bufA  (row = o_local, k = w), packed b64
#pragma unroll
    for (int i = 0; i < 4; ++i){
      int kw = r0 + 16*i + q*4;
#pragma unroll
      for (int j = 0; j < 4; ++j){
        int row = c0 + 16*j + l15;
        f32x4 v = acc1[i*4+j];
        bf16x4 pk;
        pk.x = (short)f2bf(v.x); pk.y = (short)f2bf(v.y);
        pk.z = (short)f2bf(v.z); pk.w = (short)f2bf(v.w);
        *(bf16x4*)(&bufA[swz(row, kw)]) = pk;
      }
    }
    __syncthreads();

    // ---- s2: S1^T = P^T @ M   (A = bufA rows o, k=w ; B = M rows w', k=w)
#pragma unroll
    for (int t = 0; t < 16; ++t) acc1[t] = f32x4{0.f,0.f,0.f,0.f};
#pragma unroll
    for (int ks = 0; ks < 4; ++ks){
      int kk = ks*32 + q*8;
      bf16x8 a0 = *(const bf16x8*)(&bufA[swz(r0 +  0 + l15, kk)]);
      bf16x8 a1 = *(const bf16x8*)(&bufA[swz(r0 + 16 + l15, kk)]);
      bf16x8 a2 = *(const bf16x8*)(&bufA[swz(r0 + 32 + l15, kk)]);
      bf16x8 a3 = *(const bf16x8*)(&bufA[swz(r0 + 48 + l15, kk)]);
      bf16x8 b0 = *(const bf16x8*)(Mg + (c0 +  0 + l15)*128 + kk);
      bf16x8 b1 = *(const bf16x8*)(Mg + (c0 + 16 + l15)*128 + kk);
      bf16x8 b2 = *(const bf16x8*)(Mg + (c0 + 32 + l15)*128 + kk);
      bf16x8 b3 = *(const bf16x8*)(Mg + (c0 + 48 + l15)*128 + kk);
      GEMM_STEP(acc1, a0,a1,a2,a3, b0,b1,b2,b3);
    }
    // relu(+b1), write o1 row-major [w][o] -> bufB, packed b64 (D rows = o, cols = w)
#pragma unroll
    for (int i = 0; i < 4; ++i){
      int ko = r0 + 16*i + q*4;
      float bs0 = b1base[half*128 + ko + 0];
      float bs1 = b1base[half*128 + ko + 1];
      float bs2 = b1base[half*128 + ko + 2];
      float bs3 = b1base[half*128 + ko + 3];
#pragma unroll
      for (int j = 0; j < 4; ++j){
        int row = c0 + 16*j + l15;
        f32x4 v = acc1[i*4+j];
        bf16x4 pk;
        pk.x = (short)f2bf(fmaxf(v.x + bs0, 0.f));
        pk.y = (short)f2bf(fmaxf(v.y + bs1, 0.f));
        pk.z = (short)f2bf(fmaxf(v.z + bs2, 0.f));
        pk.w = (short)f2bf(fmaxf(v.w + bs3, 0.f));
        *(bf16x4*)(&bufB[swz(row, ko)]) = pk;
      }
    }
    __syncthreads();

    // ---- s3: o2 += o1 @ W2half  (A = bufB rows w, k=o ; B = W2et rows c', k=o)
#pragma unroll
    for (int ks = 0; ks < 4; ++ks){
      int kk = ks*32 + q*8;
      bf16x8 a0 = *(const bf16x8*)(&bufB[swz(r0 +  0 + l15, kk)]);
      bf16x8 a1 = *(const bf16x8*)(&bufB[swz(r0 + 16 + l15, kk)]);
      bf16x8 a2 = *(const bf16x8*)(&bufB[swz(r0 + 32 + l15, kk)]);
      bf16x8 a3 = *(const bf16x8*)(&bufB[swz(r0 + 48 + l15, kk)]);
      const u16* wb = W2base + (c0 + l15)*256 + half*128 + kk;
      bf16x8 b0 = *(const bf16x8*)(wb);
      bf16x8 b1 = *(const bf16x8*)(wb + 16*256);
      bf16x8 b2 = *(const bf16x8*)(wb + 32*256);
      bf16x8 b3 = *(const bf16x8*)(wb + 48*256);
      GEMM_STEP(acc2, a0,a1,a2,a3, b0,b1,b2,b3);
    }
    __syncthreads();
  }

  // ---- +b2, soft-threshold, write T^T -> bufA (row = c', k = w), packed b64
  {
    float b2v[4];
#pragma unroll
    for (int j = 0; j < 4; ++j) b2v[j] = b2base[c0 + 16*j + l15];
#pragma unroll
    for (int i = 0; i < 4; ++i){
      int kw = r0 + 16*i + q*4;
#pragma unroll
      for (int j = 0; j < 4; ++j){
        int row = c0 + 16*j + l15;
        f32x4 v = acc2[i*4+j];
        float t0 = v.x + b2v[j], t1 = v.y + b2v[j], t2 = v.z + b2v[j], t3 = v.w + b2v[j];
        float m0 = fmaxf(fabsf(t0) - LAM, 0.f);
        float m1 = fmaxf(fabsf(t1) - LAM, 0.f);
        float m2 = fmaxf(fabsf(t2) - LAM, 0.f);
        float m3 = fmaxf(fabsf(t3) - LAM, 0.f);
        bf16x4 pk;
        pk.x = (short)f2bf(t0 >= 0.f ? m0 : -m0);
        pk.y = (short)f2bf(t1 >= 0.f ? m1 : -m1);
        pk.z = (short)f2bf(t2 >= 0.f ? m2 : -m2);
        pk.w = (short)f2bf(t3 >= 0.f ? m3 : -m3);
        *(bf16x4*)(&bufA[swz(row, kw)]) = pk;
      }
    }
  }
  __syncthreads();

  // ---- s4: U = M @ T   (A = M rows w'', k=w ; B = bufA rows c', k=w)
#pragma unroll
  for (int t = 0; t < 16; ++t) acc1[t] = f32x4{0.f,0.f,0.f,0.f};
#pragma unroll
  for (int ks = 0; ks < 4; ++ks){
    int kk = ks*32 + q*8;
    bf16x8 a0 = *(const bf16x8*)(Mg + (r0 +  0 + l15)*128 + kk);
    bf16x8 a1 = *(const bf16x8*)(Mg + (r0 + 16 + l15)*128 + kk);
    bf16x8 a2 = *(const bf16x8*)(Mg + (r0 + 32 + l15)*128 + kk);
    bf16x8 a3 = *(const bf16x8*)(Mg + (r0 + 48 + l15)*128 + kk);
    bf16x8 b0 = *(const bf16x8*)(&bufA[swz(c0 +  0 + l15, kk)]);
    bf16x8 b1 = *(const bf16x8*)(&bufA[swz(c0 + 16 + l15, kk)]);
    bf16x8 b2 = *(const bf16x8*)(&bufA[swz(c0 + 32 + l15, kk)]);
    bf16x8 b3 = *(const bf16x8*)(&bufA[swz(c0 + 48 + l15, kk)]);
    GEMM_STEP(acc1, a0,a1,a2,a3, b0,b1,b2,b3);
  }
  // stage U row-major [w''][c'] -> bufB
#pragma unroll
  for (int i = 0; i < 4; ++i){
    int rb = r0 + 16*i + q*4;
#pragma unroll
    for (int j = 0; j < 4; ++j){
      int col = c0 + 16*j + l15;
      f32x4 v = acc1[i*4+j];
      bufB[swz(rb+0, col)] = f2bf(v.x);
      bufB[swz(rb+1, col)] = f2bf(v.y);
      bufB[swz(rb+2, col)] = f2bf(v.z);
      bufB[swz(rb+3, col)] = f2bf(v.w);
    }
  }
  __syncthreads();
  u16* Ubase = Ug + ((b*128 + h)*128)*1024 + n*128;
#pragma unroll
  for (int it = 0; it < 8; ++it){
    int cid = it*256 + tid;
    int row = cid >> 4, cp = cid & 15;
    bf16x8 v = *(const bf16x8*)(&bufB[row*128 + (((cp ^ row) & 15) << 3)]);
    __builtin_nontemporal_store(v, (bf16x8*)(Ubase + row*1024 + cp*8));
  }
}

// ---------------- K3: out = F_H U / 16384 + x ----------------
__launch_bounds__(256, 4)
__global__ void k_dht_inv(const u16* __restrict__ Ug, const u16* __restrict__ Mg,
                          const float* __restrict__ x, float* __restrict__ out){
  __shared__ u16 ut[128*128];   // [c][h] swizzled
  int bi = blockIdx.x;
  int n = bi & 7, w = (bi >> 3) & 127, b = bi >> 10;
  int tid = threadIdx.x;
  int lane = tid & 63, wid = tid >> 6;
  int l15 = lane & 15, q = lane >> 4;
  int r0 = (wid >> 1) * 64, c0 = (wid & 1) * 64;

  {
    int cp = (tid & 63) * 2, hb = (tid >> 6) * 2;
    const u16* Ub = Ug + ((b*128)*128 + w)*1024 + n*128;
#pragma unroll
    for (int it = 0; it < 16; ++it){
      int h0 = hb + it*8;
      u32 d0 = __builtin_nontemporal_load((const u32*)(Ub + h0*131072 + cp));
      u32 d1 = __builtin_nontemporal_load((const u32*)(Ub + (h0+1)*131072 + cp));
      u32 lo = (d0 & 0xFFFFu) | ((d1 & 0xFFFFu) << 16);
      u32 hi = (d0 >> 16) | (d1 & 0xFFFF0000u);
      *(u32*)(&ut[swz(cp,   h0)]) = lo;
      *(u32*)(&ut[swz(cp+1, h0)]) = hi;
    }
  }
  __syncthreads();

  f32x4 acc[16];
#pragma unroll
  for (int t = 0; t < 16; ++t) acc[t] = f32x4{0.f,0.f,0.f,0.f};

#pragma unroll
  for (int ks = 0; ks < 4; ++ks){
    int kk = ks*32 + q*8;
    bf16x8 a0 = *(const bf16x8*)(Mg + (r0 +  0 + l15)*128 + kk);
    bf16x8 a1 = *(const bf16x8*)(Mg + (r0 + 16 + l15)*128 + kk);
    bf16x8 a2 = *(const bf16x8*)(Mg + (r0 + 32 + l15)*128 + kk);
    bf16x8 a3 = *(const bf16x8*)(Mg + (r0 + 48 + l15)*128 + kk);
    bf16x8 b0 = *(const bf16x8*)(&ut[swz(c0 +  0 + l15, kk)]);
    bf16x8 b1 = *(const bf16x8*)(&ut[swz(c0 + 16 + l15, kk)]);
    bf16x8 b2 = *(const bf16x8*)(&ut[swz(c0 + 32 + l15, kk)]);
    bf16x8 b3 = *(const bf16x8*)(&ut[swz(c0 + 48 + l15, kk)]);
    GEMM_STEP(acc, a0,a1,a2,a3, b0,b1,b2,b3);
  }

  const float s = 1.f / 16384.f;
  int gbase = ((b*128)*128 + w)*1024 + n*128;
#pragma unroll
  for (int i = 0; i < 4; ++i){
    int hh = r0 + 16*i + q*4;
#pragma unroll
    for (int j = 0; j < 4; ++j){
      int cc = c0 + 16*j + l15;
      f32x4 v = acc[i*4+j];
      int i0 = gbase + (hh+0)*131072 + cc;
      int i1 = gbase + (hh+1)*131072 + cc;
      int i2 = gbase + (hh+2)*131072 + cc;
      int i3 = gbase + (hh+3)*131072 + cc;
      float x0 = __builtin_nontemporal_load(x + i0);
      float x1 = __builtin_nontemporal_load(x + i1);
      float x2 = __builtin_nontemporal_load(x + i2);
      float x3 = __builtin_nontemporal_load(x + i3);
      __builtin_nontemporal_store(v.x * s + x0, out + i0);
      __builtin_nontemporal_store(v.y * s + x1, out + i1);
      __builtin_nontemporal_store(v.z * s + x2, out + i2);
      __builtin_nontemporal_store(v.w * s + x3, out + i3);
    }
  }
}

extern "C" void kernel_launch(void* const* d_in, const int* in_sizes, int n_in,
                              void* d_out, int out_size, void* d_ws, size_t ws_size,
                              hipStream_t stream) {
  const float* x  = (const float*)d_in[0];
  const float* w1 = (const float*)d_in[1];
  const float* b1 = (const float*)d_in[2];
  const float* w2 = (const float*)d_in[3];
  const float* b2 = (const float*)d_in[4];
  float* out = (float*)d_out;

  // A intermediate (bf16) in first 134.2MB of d_out; folded weights in its tail.
  u16* Ag   = (u16*)d_out;
  u16* W1et = (u16*)((char*)d_out + 267386880);   // 512 KB
  u16* W2et = (u16*)((char*)d_out + 267911168);   // 512 KB
  // U intermediate (bf16) + cas matrix in workspace (~134.3 MB needed).
  u16* Ug   = (u16*)d_ws;
  u16* Mg   = (u16*)((char*)d_ws + 134217728);

  k_prep<<<2112, 256, 0, stream>>>(w1, w2, Mg, W1et, W2et);
  k_dht_fwd<<<4096, 256, 0, stream>>>(x, Mg, Ag);
  k_mlp<<<4096, 256, 0, stream>>>(Ag, W1et, W2et, Mg, b1, b2, Ug);
  k_dht_inv<<<4096, 256, 0, stream>>>(Ug, Mg, x, out);
}

// Round 3
// 989.342 us; speedup vs baseline: 1.3312x; 1.0831x over previous
//
#include <hip/hip_runtime.h>

typedef unsigned short u16;
typedef unsigned int   u32;
typedef __attribute__((ext_vector_type(8))) short bf16x8;
typedef __attribute__((ext_vector_type(4))) short bf16x4;
typedef __attribute__((ext_vector_type(4))) float f32x4;

#define LAM 0.01f

__device__ __forceinline__ u16 f2bf(float f){
  u32 u = __float_as_uint(f);
  u = u + 0x7FFFu + ((u >> 16) & 1u);
  return (u16)(u >> 16);
}

// swizzled LDS index for a [row][k] tile, pitch 128 u16; 16B chunks XOR'ed by row&15
__device__ __forceinline__ int swz(int row, int k){
  return row*128 + ((((k >> 3) ^ row) & 15) << 3) + (k & 7);
}

#define MFMA16(ac, a, b) ac = __builtin_amdgcn_mfma_f32_16x16x32_bf16((a), (b), (ac), 0, 0, 0)

#define GEMM_STEP(acc, A0,A1,A2,A3, B0,B1,B2,B3) \
  MFMA16(acc[0], A0,B0); MFMA16(acc[1], A0,B1); MFMA16(acc[2], A0,B2); MFMA16(acc[3], A0,B3); \
  MFMA16(acc[4], A1,B0); MFMA16(acc[5], A1,B1); MFMA16(acc[6], A1,B2); MFMA16(acc[7], A1,B3); \
  MFMA16(acc[8], A2,B0); MFMA16(acc[9], A2,B1); MFMA16(acc[10],A2,B2); MFMA16(acc[11],A2,B3); \
  MFMA16(acc[12],A3,B0); MFMA16(acc[13],A3,B1); MFMA16(acc[14],A3,B2); MFMA16(acc[15],A3,B3);

// 4 A-frags x 2 B-frags
#define GEMM_STEP42(acc, A0,A1,A2,A3, B0,B1) \
  MFMA16(acc[0], A0,B0); MFMA16(acc[1], A0,B1); \
  MFMA16(acc[2], A1,B0); MFMA16(acc[3], A1,B1); \
  MFMA16(acc[4], A2,B0); MFMA16(acc[5], A2,B1); \
  MFMA16(acc[6], A3,B0); MFMA16(acc[7], A3,B1);

// ---------------- prep: cas matrix + folded transposed weights ----------------
__global__ void k_prep(const float* __restrict__ w1, const float* __restrict__ w2,
                       u16* __restrict__ Mg, u16* __restrict__ W1et, u16* __restrict__ W2et){
  int gid = blockIdx.x * 256 + threadIdx.x;
  if (gid < 16384){
    int i = gid >> 7, j = gid & 127;
    int t = (i * j) & 127;                       // exact periodic reduction
    float ang = (float)t * 0.04908738521234052f; // 2*pi/128
    Mg[gid] = f2bf(cosf(ang) + sinf(ang));
  } else if (gid < 16384 + 262144){
    int e = gid - 16384;                 // W1et[n][o][i] = w1[0,n,i,o] + w1[1,n,i,o]
    int n = e >> 15, o = (e >> 7) & 255, i = e & 127;
    float v = w1[(n*128 + i)*256 + o] + w1[((8+n)*128 + i)*256 + o];
    W1et[e] = f2bf(v);
  } else {
    int e = gid - (16384 + 262144);      // W2et[n][i][o] = w2[0,n,o,i] + w2[1,n,o,i]
    int n = e >> 15, i = (e >> 8) & 127, o = e & 255;
    float v = w2[(n*256 + o)*128 + i] + w2[((8+n)*256 + o)*128 + i];
    W2et[e] = f2bf(v);
  }
}

// ---------------- K1: A = F_H x  (per-(b,w,n) tile) ----------------
__launch_bounds__(256, 4)
__global__ void k_dht_fwd(const float* __restrict__ x, const u16* __restrict__ Mg,
                          u16* __restrict__ Ag){
  __shared__ u16 xt[128*128];   // [c][h] swizzled, later reused as [h'][c] staging
  int bi = blockIdx.x;
  int n = bi & 7, w = (bi >> 3) & 127, b = bi >> 10;
  int tid = threadIdx.x;
  int lane = tid & 63, wid = tid >> 6;
  int l15 = lane & 15, q = lane >> 4;
  int r0 = (wid >> 1) * 64, c0 = (wid & 1) * 64;

  // load + transpose + convert: x[b][h][w][n*128+c] -> xt[c][h]
  {
    int c = tid & 127, hg = tid >> 7;
    const float* xb = x + ((b*128)*128 + w)*1024 + n*128 + c;
    for (int it = 0; it < 32; ++it){
      int h0 = (hg + 2*it) * 2;
      float v0 = __builtin_nontemporal_load(xb + h0 * 131072);
      float v1 = __builtin_nontemporal_load(xb + (h0+1) * 131072);
      u32 pk = (u32)f2bf(v0) | ((u32)f2bf(v1) << 16);
      *(u32*)(&xt[swz(c, h0)]) = pk;
    }
  }
  __syncthreads();

  f32x4 acc[16];
#pragma unroll
  for (int t = 0; t < 16; ++t) acc[t] = f32x4{0.f,0.f,0.f,0.f};

#pragma unroll
  for (int ks = 0; ks < 4; ++ks){
    int kk = ks*32 + q*8;
    bf16x8 a0 = *(const bf16x8*)(Mg + (r0 +  0 + l15)*128 + kk);
    bf16x8 a1 = *(const bf16x8*)(Mg + (r0 + 16 + l15)*128 + kk);
    bf16x8 a2 = *(const bf16x8*)(Mg + (r0 + 32 + l15)*128 + kk);
    bf16x8 a3 = *(const bf16x8*)(Mg + (r0 + 48 + l15)*128 + kk);
    bf16x8 b0 = *(const bf16x8*)(&xt[swz(c0 +  0 + l15, kk)]);
    bf16x8 b1 = *(const bf16x8*)(&xt[swz(c0 + 16 + l15, kk)]);
    bf16x8 b2 = *(const bf16x8*)(&xt[swz(c0 + 32 + l15, kk)]);
    bf16x8 b3 = *(const bf16x8*)(&xt[swz(c0 + 48 + l15, kk)]);
    GEMM_STEP(acc, a0,a1,a2,a3, b0,b1,b2,b3);
  }
  __syncthreads();   // all xt fragment reads done before staging overwrites it

  // stage D[h'][c] into LDS then coalesced store
#pragma unroll
  for (int i = 0; i < 4; ++i){
    int rb = r0 + 16*i + q*4;
#pragma unroll
    for (int j = 0; j < 4; ++j){
      int col = c0 + 16*j + l15;
      f32x4 v = acc[i*4+j];
      xt[swz(rb+0, col)] = f2bf(v.x);
      xt[swz(rb+1, col)] = f2bf(v.y);
      xt[swz(rb+2, col)] = f2bf(v.z);
      xt[swz(rb+3, col)] = f2bf(v.w);
    }
  }
  __syncthreads();
  u16* Aout = Ag + ((b*128)*128 + w)*1024 + n*128;
#pragma unroll
  for (int it = 0; it < 8; ++it){
    int cid = it*256 + tid;
    int row = cid >> 4, cp = cid & 15;
    bf16x8 v = *(const bf16x8*)(&xt[row*128 + (((cp ^ row) & 15) << 3)]);
    __builtin_nontemporal_store(v, (bf16x8*)(Aout + row*131072 + cp*8));
  }
}

// ---------------- K2 fused: F_W -> MLP -> threshold -> F_W (per-(b,h,n) tile) ----------------
// 8 waves (512 thr), wave tile 64x32 (2r x 4c), acc1+acc2 = 64 regs.
// X staged once into LDS; single 32KB staging buffer; forced 16 waves/CU.
__launch_bounds__(512, 4)
__global__ void k_mlp(const u16* __restrict__ Xg, const u16* __restrict__ W1et,
                      const u16* __restrict__ W2et, const u16* __restrict__ Mg,
                      const float* __restrict__ b1g, const float* __restrict__ b2g,
                      u16* __restrict__ Ug){
  __shared__ u16 Xt[128*128];    // X tile [w][c] swizzled (32 KB), lives whole kernel
  __shared__ u16 buf[128*128];   // staging: P^T -> o1 -> T^T -> U (32 KB)
  int bi = blockIdx.x;
  int n = bi & 7, h = (bi >> 3) & 127, b = bi >> 10;
  int tid = threadIdx.x;
  int lane = tid & 63, wid = tid >> 6;          // 0..7
  int l15 = lane & 15, q = lane >> 4;
  int r0 = (wid >> 2) * 64;                     // {0,64}
  int c0 = (wid & 3) * 32;                      // {0,32,64,96}

  const u16*  Xbase  = Xg + ((b*128 + h)*128)*1024 + n*128;   // + w*1024 + c
  const u16*  W1base = W1et + n*256*128;                      // [o][c], pitch 128
  const u16*  W2base = W2et + n*128*256;                      // [c'][o], pitch 256
  const float* b1base = b1g + n*256;
  const float* b2base = b2g + n*128;

  // cooperative X load -> Xt [w][c] swizzled, NT (streaming, no global reuse)
  {
    int c16 = tid & 15, rbase = tid >> 4;       // 32 rows per iter
#pragma unroll
    for (int it = 0; it < 4; ++it){
      int r = rbase + it*32;
      bf16x8 v = __builtin_nontemporal_load((const bf16x8*)(Xbase + r*1024 + c16*8));
      *(bf16x8*)(&Xt[swz(r, c16*8)]) = v;
    }
  }
  __syncthreads();

  f32x4 acc2[8], acc1[8];
#pragma unroll
  for (int t = 0; t < 8; ++t) acc2[t] = f32x4{0.f,0.f,0.f,0.f};

  for (int half = 0; half < 2; ++half){
    // ---- s1: P = X @ W1half  (A = Xt rows w, k=c ; B = W1et rows o, k=c)
#pragma unroll
    for (int t = 0; t < 8; ++t) acc1[t] = f32x4{0.f,0.f,0.f,0.f};
#pragma unroll
    for (int ks = 0; ks < 4; ++ks){
      int kk = ks*32 + q*8;
      bf16x8 a0 = *(const bf16x8*)(&Xt[swz(r0 +  0 + l15, kk)]);
      bf16x8 a1 = *(const bf16x8*)(&Xt[swz(r0 + 16 + l15, kk)]);
      bf16x8 a2 = *(const bf16x8*)(&Xt[swz(r0 + 32 + l15, kk)]);
      bf16x8 a3 = *(const bf16x8*)(&Xt[swz(r0 + 48 + l15, kk)]);
      const u16* wb = W1base + (half*128 + c0 + l15)*128 + kk;
      bf16x8 b0 = *(const bf16x8*)(wb);
      bf16x8 b1 = *(const bf16x8*)(wb + 16*128);
      GEMM_STEP42(acc1, a0,a1,a2,a3, b0,b1);
    }
    __syncthreads();   // prev readers of buf (s3 of prev half) done
    // write P^T -> buf (row = o_local, k = w)
#pragma unroll
    for (int i = 0; i < 4; ++i){
      int kw = r0 + 16*i + q*4;
#pragma unroll
      for (int j = 0; j < 2; ++j){
        int row = c0 + 16*j + l15;
        f32x4 v = acc1[i*2+j];
        bf16x4 pk;
        pk.x = (short)f2bf(v.x); pk.y = (short)f2bf(v.y);
        pk.z = (short)f2bf(v.z); pk.w = (short)f2bf(v.w);
        *(bf16x4*)(&buf[swz(row, kw)]) = pk;
      }
    }
    __syncthreads();

    // ---- s2: S1^T = P^T @ M  (A = buf rows o, k=w ; B = M rows w', k=w)
#pragma unroll
    for (int t = 0; t < 8; ++t) acc1[t] = f32x4{0.f,0.f,0.f,0.f};
#pragma unroll
    for (int ks = 0; ks < 4; ++ks){
      int kk = ks*32 + q*8;
      bf16x8 a0 = *(const bf16x8*)(&buf[swz(r0 +  0 + l15, kk)]);
      bf16x8 a1 = *(const bf16x8*)(&buf[swz(r0 + 16 + l15, kk)]);
      bf16x8 a2 = *(const bf16x8*)(&buf[swz(r0 + 32 + l15, kk)]);
      bf16x8 a3 = *(const bf16x8*)(&buf[swz(r0 + 48 + l15, kk)]);
      bf16x8 b0 = *(const bf16x8*)(Mg + (c0 +  0 + l15)*128 + kk);
      bf16x8 b1 = *(const bf16x8*)(Mg + (c0 + 16 + l15)*128 + kk);
      GEMM_STEP42(acc1, a0,a1,a2,a3, b0,b1);
    }
    __syncthreads();   // s2 reads of buf done before o1 overwrites
    // relu(+b1), write o1 row-major [w'][o] -> buf
#pragma unroll
    for (int i = 0; i < 4; ++i){
      int ko = r0 + 16*i + q*4;
      float bs0 = b1base[half*128 + ko + 0];
      float bs1 = b1base[half*128 + ko + 1];
      float bs2 = b1base[half*128 + ko + 2];
      float bs3 = b1base[half*128 + ko + 3];
#pragma unroll
      for (int j = 0; j < 2; ++j){
        int row = c0 + 16*j + l15;
        f32x4 v = acc1[i*2+j];
        bf16x4 pk;
        pk.x = (short)f2bf(fmaxf(v.x + bs0, 0.f));
        pk.y = (short)f2bf(fmaxf(v.y + bs1, 0.f));
        pk.z = (short)f2bf(fmaxf(v.z + bs2, 0.f));
        pk.w = (short)f2bf(fmaxf(v.w + bs3, 0.f));
        *(bf16x4*)(&buf[swz(row, ko)]) = pk;
      }
    }
    __syncthreads();

    // ---- s3: o2 += o1 @ W2half  (A = buf rows w', k=o ; B = W2et rows c', k=o)
#pragma unroll
    for (int ks = 0; ks < 4; ++ks){
      int kk = ks*32 + q*8;
      bf16x8 a0 = *(const bf16x8*)(&buf[swz(r0 +  0 + l15, kk)]);
      bf16x8 a1 = *(const bf16x8*)(&buf[swz(r0 + 16 + l15, kk)]);
      bf16x8 a2 = *(const bf16x8*)(&buf[swz(r0 + 32 + l15, kk)]);
      bf16x8 a3 = *(const bf16x8*)(&buf[swz(r0 + 48 + l15, kk)]);
      const u16* wb = W2base + (c0 + l15)*256 + half*128 + kk;
      bf16x8 b0 = *(const bf16x8*)(wb);
      bf16x8 b1 = *(const bf16x8*)(wb + 16*256);
      GEMM_STEP42(acc2, a0,a1,a2,a3, b0,b1);
    }
    __syncthreads();   // s3 reads done; next half may overwrite buf
  }

  // ---- +b2, soft-threshold, write T^T -> buf (row = c', k = w)
  {
    float b2v0 = b2base[c0 +  0 + l15];
    float b2v1 = b2base[c0 + 16 + l15];
#pragma unroll
    for (int i = 0; i < 4; ++i){
      int kw = r0 + 16*i + q*4;
#pragma unroll
      for (int j = 0; j < 2; ++j){
        int row = c0 + 16*j + l15;
        float bb = j ? b2v1 : b2v0;
        f32x4 v = acc2[i*2+j];
        float t0 = v.x + bb, t1 = v.y + bb, t2 = v.z + bb, t3 = v.w + bb;
        float m0 = fmaxf(fabsf(t0) - LAM, 0.f);
        float m1 = fmaxf(fabsf(t1) - LAM, 0.f);
        float m2 = fmaxf(fabsf(t2) - LAM, 0.f);
        float m3 = fmaxf(fabsf(t3) - LAM, 0.f);
        bf16x4 pk;
        pk.x = (short)f2bf(t0 >= 0.f ? m0 : -m0);
        pk.y = (short)f2bf(t1 >= 0.f ? m1 : -m1);
        pk.z = (short)f2bf(t2 >= 0.f ? m2 : -m2);
        pk.w = (short)f2bf(t3 >= 0.f ? m3 : -m3);
        *(bf16x4*)(&buf[swz(row, kw)]) = pk;
      }
    }
  }
  __syncthreads();

  // ---- s4: U = M @ T  (A = M rows w'', k=w ; B = buf rows c', k=w)
#pragma unroll
  for (int t = 0; t < 8; ++t) acc1[t] = f32x4{0.f,0.f,0.f,0.f};
#pragma unroll
  for (int ks = 0; ks < 4; ++ks){
    int kk = ks*32 + q*8;
    bf16x8 a0 = *(const bf16x8*)(Mg + (r0 +  0 + l15)*128 + kk);
    bf16x8 a1 = *(const bf16x8*)(Mg + (r0 + 16 + l15)*128 + kk);
    bf16x8 a2 = *(const bf16x8*)(Mg + (r0 + 32 + l15)*128 + kk);
    bf16x8 a3 = *(const bf16x8*)(Mg + (r0 + 48 + l15)*128 + kk);
    bf16x8 b0 = *(const bf16x8*)(&buf[swz(c0 +  0 + l15, kk)]);
    bf16x8 b1 = *(const bf16x8*)(&buf[swz(c0 + 16 + l15, kk)]);
    GEMM_STEP42(acc1, a0,a1,a2,a3, b0,b1);
  }
  __syncthreads();   // s4 reads of buf done before U staging overwrites
  // stage U row-major [w''][c'] -> buf
#pragma unroll
  for (int i = 0; i < 4; ++i){
    int rb = r0 + 16*i + q*4;
#pragma unroll
    for (int j = 0; j < 2; ++j){
      int col = c0 + 16*j + l15;
      f32x4 v = acc1[i*2+j];
      buf[swz(rb+0, col)] = f2bf(v.x);
      buf[swz(rb+1, col)] = f2bf(v.y);
      buf[swz(rb+2, col)] = f2bf(v.z);
      buf[swz(rb+3, col)] = f2bf(v.w);
    }
  }
  __syncthreads();
  u16* Ubase = Ug + ((b*128 + h)*128)*1024 + n*128;
#pragma unroll
  for (int it = 0; it < 4; ++it){
    int cid = it*512 + tid;
    int row = cid >> 4, cp = cid & 15;
    bf16x8 v = *(const bf16x8*)(&buf[row*128 + (((cp ^ row) & 15) << 3)]);
    __builtin_nontemporal_store(v, (bf16x8*)(Ubase + row*1024 + cp*8));
  }
}

// ---------------- K3: out = F_H U / 16384 + x ----------------
__launch_bounds__(256, 4)
__global__ void k_dht_inv(const u16* __restrict__ Ug, const u16* __restrict__ Mg,
                          const float* __restrict__ x, float* __restrict__ out){
  __shared__ u16 ut[128*128];   // [c][h] swizzled
  int bi = blockIdx.x;
  int n = bi & 7, w = (bi >> 3) & 127, b = bi >> 10;
  int tid = threadIdx.x;
  int lane = tid & 63, wid = tid >> 6;
  int l15 = lane & 15, q = lane >> 4;
  int r0 = (wid >> 1) * 64, c0 = (wid & 1) * 64;

  {
    int cp = (tid & 63) * 2, hb = (tid >> 6) * 2;
    const u16* Ub = Ug + ((b*128)*128 + w)*1024 + n*128;
#pragma unroll
    for (int it = 0; it < 16; ++it){
      int h0 = hb + it*8;
      u32 d0 = __builtin_nontemporal_load((const u32*)(Ub + h0*131072 + cp));
      u32 d1 = __builtin_nontemporal_load((const u32*)(Ub + (h0+1)*131072 + cp));
      u32 lo = (d0 & 0xFFFFu) | ((d1 & 0xFFFFu) << 16);
      u32 hi = (d0 >> 16) | (d1 & 0xFFFF0000u);
      *(u32*)(&ut[swz(cp,   h0)]) = lo;
      *(u32*)(&ut[swz(cp+1, h0)]) = hi;
    }
  }
  __syncthreads();

  f32x4 acc[16];
#pragma unroll
  for (int t = 0; t < 16; ++t) acc[t] = f32x4{0.f,0.f,0.f,0.f};

#pragma unroll
  for (int ks = 0; ks < 4; ++ks){
    int kk = ks*32 + q*8;
    bf16x8 a0 = *(const bf16x8*)(Mg + (r0 +  0 + l15)*128 + kk);
    bf16x8 a1 = *(const bf16x8*)(Mg + (r0 + 16 + l15)*128 + kk);
    bf16x8 a2 = *(const bf16x8*)(Mg + (r0 + 32 + l15)*128 + kk);
    bf16x8 a3 = *(const bf16x8*)(Mg + (r0 + 48 + l15)*128 + kk);
    bf16x8 b0 = *(const bf16x8*)(&ut[swz(c0 +  0 + l15, kk)]);
    bf16x8 b1 = *(const bf16x8*)(&ut[swz(c0 + 16 + l15, kk)]);
    bf16x8 b2 = *(const bf16x8*)(&ut[swz(c0 + 32 + l15, kk)]);
    bf16x8 b3 = *(const bf16x8*)(&ut[swz(c0 + 48 + l15, kk)]);
    GEMM_STEP(acc, a0,a1,a2,a3, b0,b1,b2,b3);
  }

  const float s = 1.f / 16384.f;
  int gbase = ((b*128)*128 + w)*1024 + n*128;
#pragma unroll
  for (int i = 0; i < 4; ++i){
    int hh = r0 + 16*i + q*4;
#pragma unroll
    for (int j = 0; j < 4; ++j){
      int cc = c0 + 16*j + l15;
      f32x4 v = acc[i*4+j];
      int i0 = gbase + (hh+0)*131072 + cc;
      int i1 = gbase + (hh+1)*131072 + cc;
      int i2 = gbase + (hh+2)*131072 + cc;
      int i3 = gbase + (hh+3)*131072 + cc;
      float x0 = __builtin_nontemporal_load(x + i0);
      float x1 = __builtin_nontemporal_load(x + i1);
      float x2 = __builtin_nontemporal_load(x + i2);
      float x3 = __builtin_nontemporal_load(x + i3);
      __builtin_nontemporal_store(v.x * s + x0, out + i0);
      __builtin_nontemporal_store(v.y * s + x1, out + i1);
      __builtin_nontemporal_store(v.z * s + x2, out + i2);
      __builtin_nontemporal_store(v.w * s + x3, out + i3);
    }
  }
}

extern "C" void kernel_launch(void* const* d_in, const int* in_sizes, int n_in,
                              void* d_out, int out_size, void* d_ws, size_t ws_size,
                              hipStream_t stream) {
  const float* x  = (const float*)d_in[0];
  const float* w1 = (const float*)d_in[1];
  const float* b1 = (const float*)d_in[2];
  const float* w2 = (const float*)d_in[3];
  const float* b2 = (const float*)d_in[4];
  float* out = (float*)d_out;

  // A intermediate (bf16) in first 134.2MB of d_out; folded weights in its tail.
  u16* Ag   = (u16*)d_out;
  u16* W1et = (u16*)((char*)d_out + 267386880);   // 512 KB
  u16* W2et = (u16*)((char*)d_out + 267911168);   // 512 KB
  // U intermediate (bf16) + cas matrix in workspace (~134.3 MB needed).
  u16* Ug   = (u16*)d_ws;
  u16* Mg   = (u16*)((char*)d_ws + 134217728);

  k_prep<<<2112, 256, 0, stream>>>(w1, w2, Mg, W1et, W2et);
  k_dht_fwd<<<4096, 256, 0, stream>>>(x, Mg, Ag);
  k_mlp<<<4096, 512, 0, stream>>>(Ag, W1et, W2et, Mg, b1, b2, Ug);
  k_dht_inv<<<4096, 256, 0, stream>>>(Ug, Mg, x, out);
}